// Round 5
// baseline (405.705 us; speedup 1.0000x reference)
//
#include <hip/hip_runtime.h>
#include <hip/hip_bf16.h>
#include <cstdint>
#include <cstddef>

// Problem constants
#define B_   64
#define LC_  1024
#define LQ_  128
#define D_   128

typedef __bf16 bf16;
typedef bf16  bf16x8 __attribute__((ext_vector_type(8)));
typedef bf16  bf16x4 __attribute__((ext_vector_type(4)));
typedef float f32x4  __attribute__((ext_vector_type(4)));

__device__ __forceinline__ f32x4 mfma16(bf16x8 a, bf16x8 b, f32x4 c) {
  return __builtin_amdgcn_mfma_f32_16x16x32_bf16(a, b, c, 0, 0, 0);
}

// XOR swizzle: spreads row-strided column reads across banks (16B granule).
__device__ __forceinline__ int swz(int row, int elem) { return elem ^ ((row & 7) << 3); }

// ---------------------------------------------------------------------------
// kpre = k0c (bx<8) U k0q (bx==8), grid (9, B).
//  c path: cw1[b,k] = c.w1 ; cw3 = bf16(c*w3) ; cT = bf16(c)^T
//  q path: qw2[b,j] = q.w2 ; qb = bf16(q) ; qT = bf16(q)^T ; cnt[b] = 0
// Tile padded to 136 (row stride 272 B, 16B-aligned) -> transpose staging
// uses ds_write_b128 (8/thread) instead of 64 scalar ds_write_u16.
// ---------------------------------------------------------------------------
__global__ __launch_bounds__(256) void kpre(const float* __restrict__ c, const float* __restrict__ q,
                                            const float* __restrict__ w,
                                            float* __restrict__ cw1, bf16* __restrict__ cw3,
                                            bf16* __restrict__ cT,
                                            float* __restrict__ qw2, bf16* __restrict__ qb,
                                            bf16* __restrict__ qT, int* __restrict__ cnt) {
  __shared__ float wA[128];
  __shared__ float wB[128];
  __shared__ bf16  tile[128 * 136];
  const int b = blockIdx.y, bx = blockIdx.x;
  const int t = threadIdx.x;

  if (bx < 8) {
    // ---------------- c path: 128-row k-slice ----------------
    const int k0 = bx * 128;
    if (t < 128) { wA[t] = w[t]; wB[t] = w[256 + t]; }
    __syncthreads();
    {
      const int r = t >> 1, d0 = (t & 1) * 64;
      const float* crow = c + ((size_t)(b * LC_ + k0 + r) * D_ + d0);
      bf16* orow = cw3 + ((size_t)(b * LC_ + k0 + r) * D_ + d0);
      float dot = 0.f;
#pragma unroll
      for (int v = 0; v < 8; ++v) {
        const float4 f0 = ((const float4*)crow)[v * 2 + 0];
        const float4 f1 = ((const float4*)crow)[v * 2 + 1];
        const int dd = d0 + v * 8;
        dot += f0.x * wA[dd + 0] + f0.y * wA[dd + 1] + f0.z * wA[dd + 2] + f0.w * wA[dd + 3]
             + f1.x * wA[dd + 4] + f1.y * wA[dd + 5] + f1.z * wA[dd + 6] + f1.w * wA[dd + 7];
        bf16x8 oc, o;
        oc[0] = (bf16)f0.x; oc[1] = (bf16)f0.y; oc[2] = (bf16)f0.z; oc[3] = (bf16)f0.w;
        oc[4] = (bf16)f1.x; oc[5] = (bf16)f1.y; oc[6] = (bf16)f1.z; oc[7] = (bf16)f1.w;
        o[0] = (bf16)(f0.x * wB[dd + 0]); o[1] = (bf16)(f0.y * wB[dd + 1]);
        o[2] = (bf16)(f0.z * wB[dd + 2]); o[3] = (bf16)(f0.w * wB[dd + 3]);
        o[4] = (bf16)(f1.x * wB[dd + 4]); o[5] = (bf16)(f1.y * wB[dd + 5]);
        o[6] = (bf16)(f1.z * wB[dd + 6]); o[7] = (bf16)(f1.w * wB[dd + 7]);
        *(bf16x8*)&tile[r * 136 + dd] = oc;
        *(bf16x8*)(orow + v * 8) = o;
      }
      dot += __shfl_xor(dot, 1);
      if ((t & 1) == 0) cw1[b * LC_ + k0 + r] = dot;
    }
    __syncthreads();
    {
      const int d = t >> 1, kh = (t & 1) * 64;
      bf16* trow = cT + ((size_t)(b * D_ + d) * LC_ + k0 + kh);
#pragma unroll
      for (int v = 0; v < 8; ++v) {
        bf16x8 o;
#pragma unroll
        for (int e = 0; e < 8; ++e) o[e] = tile[(kh + v * 8 + e) * 136 + d];
        *(bf16x8*)(trow + v * 8) = o;
      }
    }
  } else {
    // ---------------- q path: whole batch ----------------
    if (t < 128) wA[t] = w[128 + t];
    if (t == 0) cnt[b] = 0;          // reset k1 reduction counter for this batch
    __syncthreads();
    {
      const int r = t >> 1, d0 = (t & 1) * 64;
      const float* qrow = q + ((size_t)(b * LQ_ + r) * D_ + d0);
      bf16* orow = qb + ((size_t)(b * LQ_ + r) * D_ + d0);
      float dot = 0.f;
#pragma unroll
      for (int v = 0; v < 8; ++v) {
        const float4 f0 = ((const float4*)qrow)[v * 2 + 0];
        const float4 f1 = ((const float4*)qrow)[v * 2 + 1];
        const int dd = d0 + v * 8;
        dot += f0.x * wA[dd + 0] + f0.y * wA[dd + 1] + f0.z * wA[dd + 2] + f0.w * wA[dd + 3]
             + f1.x * wA[dd + 4] + f1.y * wA[dd + 5] + f1.z * wA[dd + 6] + f1.w * wA[dd + 7];
        bf16x8 o;
        o[0] = (bf16)f0.x; o[1] = (bf16)f0.y; o[2] = (bf16)f0.z; o[3] = (bf16)f0.w;
        o[4] = (bf16)f1.x; o[5] = (bf16)f1.y; o[6] = (bf16)f1.z; o[7] = (bf16)f1.w;
        *(bf16x8*)&tile[r * 136 + dd] = o;
        *(bf16x8*)(orow + v * 8) = o;
      }
      dot += __shfl_xor(dot, 1);
      if ((t & 1) == 0) qw2[b * LQ_ + r] = dot;
    }
    __syncthreads();
    {
      const int d = t >> 1, jh = (t & 1) * 64;
      bf16* trow = qT + ((size_t)(b * D_ + d) * LQ_ + jh);
#pragma unroll
      for (int v = 0; v < 8; ++v) {
        bf16x8 o;
#pragma unroll
        for (int e = 0; e < 8; ++e) o[e] = tile[(jh + v * 8 + e) * 136 + d];
        *(bf16x8*)(trow + v * 8) = o;
      }
    }
  }
}

// ---------------------------------------------------------------------------
// K1 = k1p v2 + fused last-block-per-batch reduction (absorbs k1r).
// Per (b, ks in 0..7, jh in 0..1): 128 k-rows x 64 j, partials to Tpart/lpart.
// The 16th block of each batch to finish reduces the 8 k-partials,
// normalizes by l_j, and emits TT = bf16(T)^T (threadfence/atomic handoff).
// ---------------------------------------------------------------------------
__global__ __launch_bounds__(256) void k1(const float* __restrict__ cw1, const float* __restrict__ qw2,
                                          const int* __restrict__ cmask,
                                          const bf16* __restrict__ cw3, const bf16* __restrict__ cT,
                                          const bf16* __restrict__ qb,
                                          float* __restrict__ Tpart, float* __restrict__ lpart,
                                          int* __restrict__ cnt, bf16* __restrict__ TT) {
  // union: main phase qs[64*128]=16384B | PT[64*64]=8192B | lred[256]f32=1024B (25600B)
  //        reduce phase Tsum[32*132]f32=16896B | linv 128B                     (17024B)
  __shared__ __align__(16) char smem[25600];
  bf16* qs = (bf16*)smem;              // [j][d] swizzled
  bf16* PT = (bf16*)(smem + 16384);    // [j][k] swizzled
  float* lred = (float*)(smem + 24576);// [4*64] flat: lred[wk*64 + j]
  float* Tsum = (float*)smem;          // reduce phase
  float* linv = (float*)(smem + 16896);
  __shared__ int lastFlag;

  const int bx = blockIdx.x;
  const int ks = bx >> 1, jh = bx & 1;
  const int b = blockIdx.y;
  const int j0g = jh * 64;
  const int t = threadIdx.x;
  const int wk = t >> 6, lane = t & 63, quad = lane >> 4, l15 = lane & 15;

#pragma unroll
  for (int idx = t; idx < 1024; idx += 256) {
    const int row = idx >> 4, ch = idx & 15;
    *(bf16x8*)&qs[row * 128 + swz(row, ch * 8)] =
        *(const bf16x8*)(qb + ((size_t)(b * LQ_ + j0g + row) * D_ + ch * 8));
  }
  const f32x4 z = {0.f, 0.f, 0.f, 0.f};
  f32x4 Tacc[4][2];
#pragma unroll
  for (int jt = 0; jt < 4; ++jt) { Tacc[jt][0] = z; Tacc[jt][1] = z; }
  float lacc[4] = {0.f, 0.f, 0.f, 0.f};
  float qv[4];
#pragma unroll
  for (int jt = 0; jt < 4; ++jt) qv[jt] = qw2[b * LQ_ + j0g + jt * 16 + l15];
  __syncthreads();

  for (int kt = 0; kt < 2; ++kt) {
    const int k0g = ks * 128 + kt * 64;

    f32x4 S[4] = {z, z, z, z};
#pragma unroll
    for (int kk = 0; kk < 4; ++kk) {
      const bf16x8 a = *(const bf16x8*)(cw3 +
          ((size_t)(b * LC_ + k0g + wk * 16 + l15) * D_ + kk * 32 + quad * 8));
#pragma unroll
      for (int jt = 0; jt < 4; ++jt) {
        const int jr = jt * 16 + l15;
        const bf16x8 bq = *(const bf16x8*)&qs[jr * 128 + swz(jr, kk * 32 + quad * 8)];
        S[jt] = mfma16(a, bq, S[jt]);
      }
    }
    float c1v[4]; int cmv[4];
#pragma unroll
    for (int rr = 0; rr < 4; ++rr) {
      const int krow = k0g + wk * 16 + quad * 4 + rr;
      c1v[rr] = cw1[b * LC_ + krow];
      cmv[rr] = cmask[b * LC_ + krow];
    }
#pragma unroll
    for (int jt = 0; jt < 4; ++jt) {
      bf16x4 pk;
#pragma unroll
      for (int rr = 0; rr < 4; ++rr) {
        const float p = cmv[rr] ? 0.f : __expf(S[jt][rr] + c1v[rr] + qv[jt]);
        lacc[jt] += p;
        pk[rr] = (bf16)p;
      }
      const int jr = jt * 16 + l15;
      *(bf16x4*)&PT[jr * 64 + swz(jr, wk * 16 + quad * 4)] = pk;
    }
    __syncthreads();

#pragma unroll
    for (int kk = 0; kk < 2; ++kk) {
      const bf16x8 bd0 = *(const bf16x8*)(cT +
          ((size_t)(b * D_ + wk * 32 + l15) * LC_ + k0g + kk * 32 + quad * 8));
      const bf16x8 bd1 = *(const bf16x8*)(cT +
          ((size_t)(b * D_ + wk * 32 + 16 + l15) * LC_ + k0g + kk * 32 + quad * 8));
#pragma unroll
      for (int jt = 0; jt < 4; ++jt) {
        const int jr = jt * 16 + l15;
        const bf16x8 aP = *(const bf16x8*)&PT[jr * 64 + swz(jr, kk * 32 + quad * 8)];
        Tacc[jt][0] = mfma16(aP, bd0, Tacc[jt][0]);
        Tacc[jt][1] = mfma16(aP, bd1, Tacc[jt][1]);
      }
    }
    __syncthreads();
  }

#pragma unroll
  for (int jt = 0; jt < 4; ++jt) {
    lacc[jt] += __shfl_xor(lacc[jt], 16);
    lacc[jt] += __shfl_xor(lacc[jt], 32);
  }
  if (lane < 16) {
#pragma unroll
    for (int jt = 0; jt < 4; ++jt) lred[wk * 64 + jt * 16 + l15] = lacc[jt];
  }
  __syncthreads();
  if (t < 64)
    lpart[(size_t)(b * 8 + ks) * 128 + j0g + t] =
        lred[0 * 64 + t] + lred[1 * 64 + t] + lred[2 * 64 + t] + lred[3 * 64 + t];

  float* tp = Tpart + ((size_t)(b * 8 + ks)) * (128 * 128);
#pragma unroll
  for (int jt = 0; jt < 4; ++jt)
#pragma unroll
    for (int dt = 0; dt < 2; ++dt)
#pragma unroll
      for (int rr = 0; rr < 4; ++rr)
        tp[(j0g + jt * 16 + quad * 4 + rr) * 128 + wk * 32 + dt * 16 + l15] =
            Tacc[jt][dt][rr];

  // ---- last-block-per-batch reduction (replaces k1r) ----
  __threadfence();          // release this block's Tpart/lpart writes
  __syncthreads();          // all threads' writes precede the ticket
  if (t == 0) lastFlag = (atomicAdd(&cnt[b], 1) == 15);
  __syncthreads();
  if (!lastFlag) return;
  __threadfence();          // acquire other blocks' partials

  for (int js = 0; js < 4; ++js) {
    const int j0 = js * 32;
    __syncthreads();        // protect Tsum/linv reuse across quarters
#pragma unroll
    for (int idx = t; idx < 1024; idx += 256) {
      const int row = idx >> 5, seg = idx & 31;
      float4 s = {0.f, 0.f, 0.f, 0.f};
#pragma unroll
      for (int i = 0; i < 8; ++i) {
        const float4 v = ((const float4*)(Tpart + ((size_t)(b * 8 + i)) * (128 * 128)) + j0 * 32)[idx];
        s.x += v.x; s.y += v.y; s.z += v.z; s.w += v.w;
      }
      *(float4*)&Tsum[row * 132 + seg * 4] = s;
    }
    if (t < 32) {
      float l = 0.f;
#pragma unroll
      for (int i = 0; i < 8; ++i) l += lpart[(size_t)(b * 8 + i) * 128 + j0 + t];
      linv[t] = 1.f / l;
    }
    __syncthreads();
    const int d = t >> 1, jhh = (t & 1) * 16;
    bf16x8 o0, o1;
#pragma unroll
    for (int e = 0; e < 8; ++e) {
      o0[e] = (bf16)(Tsum[(jhh + e) * 132 + d] * linv[jhh + e]);
      o1[e] = (bf16)(Tsum[(jhh + 8 + e) * 132 + d] * linv[jhh + 8 + e]);
    }
    bf16* dst = TT + ((size_t)(b * D_ + d) * LQ_ + j0 + jhh);
    *(bf16x8*)dst = o0;
    *(bf16x8*)(dst + 8) = o1;
  }
}

// ---------------------------------------------------------------------------
// K2 v3 (unchanged from round 3): per (b, 64-row i-tile).
// ---------------------------------------------------------------------------
__global__ __launch_bounds__(256, 4) void k2(const float* __restrict__ c, const float* __restrict__ cw1,
                                             const float* __restrict__ qw2, const int* __restrict__ qmask,
                                             const bf16* __restrict__ cw3, const bf16* __restrict__ qb,
                                             const bf16* __restrict__ qT, const bf16* __restrict__ TT,
                                             float* __restrict__ out) {
  // union LDS: loop phase qTs/TTs/P1 = 37888 B ; epilogue A32/B32 = 33792 B
  __shared__ __align__(16) char smem[37888];
  bf16* qTs = (bf16*)(smem);             // [128][64] swizzled, current j-half
  bf16* TTs = (bf16*)(smem + 16384);     // [128][64] swizzled, current j-half
  bf16* P1  = (bf16*)(smem + 32768);     // [64][40]
  float* A32 = (float*)(smem);           // [32][132] epilogue
  float* B32 = (float*)(smem + 16896);   // [32][132] epilogue
  const int it = blockIdx.x, b = blockIdx.y;
  const int i0 = it * 64;
  const int t = threadIdx.x;
  const int w = t >> 6, lane = t & 63, quad = lane >> 4, l15 = lane & 15;

  bf16x8 aF[4];
#pragma unroll
  for (int kk = 0; kk < 4; ++kk)
    aF[kk] = *(const bf16x8*)(cw3 +
        ((size_t)(b * LC_ + i0 + w * 16 + l15) * D_ + kk * 32 + quad * 8));
  float c1v[4];
#pragma unroll
  for (int rr = 0; rr < 4; ++rr)
    c1v[rr] = cw1[b * LC_ + i0 + w * 16 + quad * 4 + rr];

  const f32x4 z = {0.f, 0.f, 0.f, 0.f};
  f32x4 Aacc[8], Bacc[8];
#pragma unroll
  for (int n = 0; n < 8; ++n) { Aacc[n] = z; Bacc[n] = z; }
  float lacc[4] = {0.f, 0.f, 0.f, 0.f};

#pragma unroll
  for (int jh = 0; jh < 2; ++jh) {
#pragma unroll
    for (int idx = t; idx < 1024; idx += 256) {
      const int row = idx >> 3, ch = idx & 7;
      const int sc = (ch * 8) ^ ((row & 7) << 3);
      *(bf16x8*)&qTs[row * 64 + sc] =
          *(const bf16x8*)(qT + ((size_t)(b * D_ + row) * LQ_ + jh * 64 + ch * 8));
      *(bf16x8*)&TTs[row * 64 + sc] =
          *(const bf16x8*)(TT + ((size_t)(b * D_ + row) * LQ_ + jh * 64 + ch * 8));
    }
    __syncthreads();

#pragma unroll
    for (int jtl = 0; jtl < 2; ++jtl) {
      const int j0 = jh * 64 + jtl * 32;
      const float qv0 = qw2[b * LQ_ + j0 + l15];
      const float qv1 = qw2[b * LQ_ + j0 + 16 + l15];
      const int   qm0 = qmask[b * LQ_ + j0 + l15];
      const int   qm1 = qmask[b * LQ_ + j0 + 16 + l15];

      f32x4 S0 = z, S1 = z;
#pragma unroll
      for (int kk = 0; kk < 4; ++kk) {
        const bf16x8 b0 = *(const bf16x8*)(qb +
            ((size_t)(b * LQ_ + j0 + l15) * D_ + kk * 32 + quad * 8));
        const bf16x8 b1 = *(const bf16x8*)(qb +
            ((size_t)(b * LQ_ + j0 + 16 + l15) * D_ + kk * 32 + quad * 8));
        S0 = mfma16(aF[kk], b0, S0);
        S1 = mfma16(aF[kk], b1, S1);
      }
#pragma unroll
      for (int rr = 0; rr < 4; ++rr) {
        const float p0 = qm0 ? 0.f : __expf(S0[rr] + c1v[rr] + qv0);
        const float p1 = qm1 ? 0.f : __expf(S1[rr] + c1v[rr] + qv1);
        lacc[rr] += p0 + p1;
        P1[(w * 16 + quad * 4 + rr) * 40 + l15] = (bf16)p0;
        P1[(w * 16 + quad * 4 + rr) * 40 + 16 + l15] = (bf16)p1;
      }
      __syncthreads();

      const bf16x8 aP = *(bf16x8*)&P1[(w * 16 + l15) * 40 + quad * 8];
      const int cbase = jtl * 32 + quad * 8;
#pragma unroll
      for (int nt = 0; nt < 8; ++nt) {
        const int row = nt * 16 + l15;
        const int sc = cbase ^ ((row & 7) << 3);
        const bf16x8 bq = *(bf16x8*)&qTs[row * 64 + sc];
        const bf16x8 bt = *(bf16x8*)&TTs[row * 64 + sc];
        Aacc[nt] = mfma16(aP, bq, Aacc[nt]);
        Bacc[nt] = mfma16(aP, bt, Bacc[nt]);
      }
      __syncthreads();
    }
  }

#pragma unroll
  for (int rr = 0; rr < 4; ++rr) {
    float v = lacc[rr];
    v += __shfl_xor(v, 1); v += __shfl_xor(v, 2);
    v += __shfl_xor(v, 4); v += __shfl_xor(v, 8);
    lacc[rr] = 1.f / v;
  }

#pragma unroll
  for (int h = 0; h < 2; ++h) {
    if ((w >> 1) == h) {
      const int lrow0 = (w & 1) * 16 + quad * 4;
#pragma unroll
      for (int nt = 0; nt < 8; ++nt)
#pragma unroll
        for (int rr = 0; rr < 4; ++rr) {
          A32[(lrow0 + rr) * 132 + nt * 16 + l15] = Aacc[nt][rr] * lacc[rr];
          B32[(lrow0 + rr) * 132 + nt * 16 + l15] = Bacc[nt][rr] * lacc[rr];
        }
    }
    __syncthreads();
#pragma unroll
    for (int idx = t; idx < 1024; idx += 256) {
      const int lrow = idx >> 5, seg = idx & 31;
      const size_t grow = (size_t)(b * LC_ + i0 + h * 32 + lrow);
      const float4 c4 = ((const float4*)(c + grow * D_))[seg];
      const float4 a4 = *(float4*)&A32[lrow * 132 + seg * 4];
      const float4 b4 = *(float4*)&B32[lrow * 132 + seg * 4];
      float4* ob = (float4*)(out + grow * 512);
      ob[seg] = c4;
      ob[32 + seg] = a4;
      float4 ca; ca.x = c4.x * a4.x; ca.y = c4.y * a4.y; ca.z = c4.z * a4.z; ca.w = c4.w * a4.w;
      ob[64 + seg] = ca;
      float4 cb; cb.x = c4.x * b4.x; cb.y = c4.y * b4.y; cb.z = c4.z * b4.z; cb.w = c4.w * b4.w;
      ob[96 + seg] = cb;
    }
    __syncthreads();
  }
}

// ---------------------------------------------------------------------------
extern "C" void kernel_launch(void* const* d_in, const int* in_sizes, int n_in,
                              void* d_out, int out_size, void* d_ws, size_t ws_size,
                              hipStream_t stream) {
  (void)in_sizes; (void)n_in; (void)out_size; (void)ws_size;
  const float* c     = (const float*)d_in[0];
  const float* q     = (const float*)d_in[1];
  const int*   cmask = (const int*)d_in[2];
  const int*   qmask = (const int*)d_in[3];
  const float* w     = (const float*)d_in[4];
  float* out = (float*)d_out;

  // workspace layout (40.1 MB)
  char* ws = (char*)d_ws;
  float* cw1 = (float*)(ws + 0);          //  64*1024 f32
  float* qw2 = (float*)(ws + 262144);     //  64*128  f32
  bf16*  cw3 = (bf16*)(ws + 294912);      //  64*1024*128 bf16  (c*w3)
  bf16*  cT  = (bf16*)(ws + 17072128);    //  64*128*1024 bf16  (c transposed)
  bf16*  qb  = (bf16*)(ws + 33849344);    //  64*128*128 bf16
  bf16*  qT  = (bf16*)(ws + 35946496);    //  64*128*128 bf16  (q transposed)
  bf16*  TT  = (bf16*)(ws + 38043648);    //  64*128*128 bf16  (T transposed)

  // k-split partials + reduction counters live in d_out scratch
  // (fully overwritten by k2 afterwards)
  float* Tpart = out;                     //  64*8*128*128 f32 = 33.6 MB
  float* lpart = out + 8388608;           //  64*8*128 f32
  int*   cnt   = (int*)(out + 8454144);   //  64 int

  kpre<<<dim3(9, 64), 256, 0, stream>>>(c, q, w, cw1, cw3, cT, qw2, qb, qT, cnt);
  k1  <<<dim3(16, 64), 256, 0, stream>>>(cw1, qw2, cmask, cw3, cT, qb, Tpart, lpart, cnt, TT);
  k2  <<<dim3(16, 64), 256, 0, stream>>>(c, cw1, qw2, qmask, cw3, qb, qT, TT, out);
}

// Round 6
// 237.713 us; speedup vs baseline: 1.7067x; 1.7067x over previous
//
#include <hip/hip_runtime.h>
#include <hip/hip_bf16.h>
#include <cstdint>
#include <cstddef>

// Problem constants
#define B_   64
#define LC_  1024
#define LQ_  128
#define D_   128

typedef __bf16 bf16;
typedef bf16  bf16x8 __attribute__((ext_vector_type(8)));
typedef bf16  bf16x4 __attribute__((ext_vector_type(4)));
typedef float f32x4  __attribute__((ext_vector_type(4)));

__device__ __forceinline__ f32x4 mfma16(bf16x8 a, bf16x8 b, f32x4 c) {
  return __builtin_amdgcn_mfma_f32_16x16x32_bf16(a, b, c, 0, 0, 0);
}

// XOR swizzle: spreads row-strided column reads across banks (16B granule).
__device__ __forceinline__ int swz(int row, int elem) { return elem ^ ((row & 7) << 3); }

// ---------------------------------------------------------------------------
// kpre = k0c (bx<8) U k0q (bx==8), grid (9, B).
//  c path: cw1[b,k] = c.w1 ; cw3 = bf16(c*w3) ; cT = bf16(c)^T
//  q path: qw2[b,j] = q.w2 ; qb = bf16(q) ; qT = bf16(q)^T
// Tile padded to 136 (row stride 272 B, 16B-aligned) -> staging uses
// ds_write_b128 instead of scalar ds_write_u16. NO fences, NO counters.
// ---------------------------------------------------------------------------
__global__ __launch_bounds__(256) void kpre(const float* __restrict__ c, const float* __restrict__ q,
                                            const float* __restrict__ w,
                                            float* __restrict__ cw1, bf16* __restrict__ cw3,
                                            bf16* __restrict__ cT,
                                            float* __restrict__ qw2, bf16* __restrict__ qb,
                                            bf16* __restrict__ qT) {
  __shared__ float wA[128];
  __shared__ float wB[128];
  __shared__ bf16  tile[128 * 136];
  const int b = blockIdx.y, bx = blockIdx.x;
  const int t = threadIdx.x;

  if (bx < 8) {
    // ---------------- c path: 128-row k-slice ----------------
    const int k0 = bx * 128;
    if (t < 128) { wA[t] = w[t]; wB[t] = w[256 + t]; }
    __syncthreads();
    {
      const int r = t >> 1, d0 = (t & 1) * 64;
      const float* crow = c + ((size_t)(b * LC_ + k0 + r) * D_ + d0);
      bf16* orow = cw3 + ((size_t)(b * LC_ + k0 + r) * D_ + d0);
      float dot = 0.f;
#pragma unroll
      for (int v = 0; v < 8; ++v) {
        const float4 f0 = ((const float4*)crow)[v * 2 + 0];
        const float4 f1 = ((const float4*)crow)[v * 2 + 1];
        const int dd = d0 + v * 8;
        dot += f0.x * wA[dd + 0] + f0.y * wA[dd + 1] + f0.z * wA[dd + 2] + f0.w * wA[dd + 3]
             + f1.x * wA[dd + 4] + f1.y * wA[dd + 5] + f1.z * wA[dd + 6] + f1.w * wA[dd + 7];
        bf16x8 oc, o;
        oc[0] = (bf16)f0.x; oc[1] = (bf16)f0.y; oc[2] = (bf16)f0.z; oc[3] = (bf16)f0.w;
        oc[4] = (bf16)f1.x; oc[5] = (bf16)f1.y; oc[6] = (bf16)f1.z; oc[7] = (bf16)f1.w;
        o[0] = (bf16)(f0.x * wB[dd + 0]); o[1] = (bf16)(f0.y * wB[dd + 1]);
        o[2] = (bf16)(f0.z * wB[dd + 2]); o[3] = (bf16)(f0.w * wB[dd + 3]);
        o[4] = (bf16)(f1.x * wB[dd + 4]); o[5] = (bf16)(f1.y * wB[dd + 5]);
        o[6] = (bf16)(f1.z * wB[dd + 6]); o[7] = (bf16)(f1.w * wB[dd + 7]);
        *(bf16x8*)&tile[r * 136 + dd] = oc;
        *(bf16x8*)(orow + v * 8) = o;
      }
      dot += __shfl_xor(dot, 1);
      if ((t & 1) == 0) cw1[b * LC_ + k0 + r] = dot;
    }
    __syncthreads();
    {
      const int d = t >> 1, kh = (t & 1) * 64;
      bf16* trow = cT + ((size_t)(b * D_ + d) * LC_ + k0 + kh);
#pragma unroll
      for (int v = 0; v < 8; ++v) {
        bf16x8 o;
#pragma unroll
        for (int e = 0; e < 8; ++e) o[e] = tile[(kh + v * 8 + e) * 136 + d];
        *(bf16x8*)(trow + v * 8) = o;
      }
    }
  } else {
    // ---------------- q path: whole batch ----------------
    if (t < 128) wA[t] = w[128 + t];
    __syncthreads();
    {
      const int r = t >> 1, d0 = (t & 1) * 64;
      const float* qrow = q + ((size_t)(b * LQ_ + r) * D_ + d0);
      bf16* orow = qb + ((size_t)(b * LQ_ + r) * D_ + d0);
      float dot = 0.f;
#pragma unroll
      for (int v = 0; v < 8; ++v) {
        const float4 f0 = ((const float4*)qrow)[v * 2 + 0];
        const float4 f1 = ((const float4*)qrow)[v * 2 + 1];
        const int dd = d0 + v * 8;
        dot += f0.x * wA[dd + 0] + f0.y * wA[dd + 1] + f0.z * wA[dd + 2] + f0.w * wA[dd + 3]
             + f1.x * wA[dd + 4] + f1.y * wA[dd + 5] + f1.z * wA[dd + 6] + f1.w * wA[dd + 7];
        bf16x8 o;
        o[0] = (bf16)f0.x; o[1] = (bf16)f0.y; o[2] = (bf16)f0.z; o[3] = (bf16)f0.w;
        o[4] = (bf16)f1.x; o[5] = (bf16)f1.y; o[6] = (bf16)f1.z; o[7] = (bf16)f1.w;
        *(bf16x8*)&tile[r * 136 + dd] = o;
        *(bf16x8*)(orow + v * 8) = o;
      }
      dot += __shfl_xor(dot, 1);
      if ((t & 1) == 0) qw2[b * LQ_ + r] = dot;
    }
    __syncthreads();
    {
      const int d = t >> 1, jh = (t & 1) * 64;
      bf16* trow = qT + ((size_t)(b * D_ + d) * LQ_ + jh);
#pragma unroll
      for (int v = 0; v < 8; ++v) {
        bf16x8 o;
#pragma unroll
        for (int e = 0; e < 8; ++e) o[e] = tile[(jh + v * 8 + e) * 136 + d];
        *(bf16x8*)(trow + v * 8) = o;
      }
    }
  }
}

// ---------------------------------------------------------------------------
// K1 (= round-3 k1p, verbatim; no fences): per (b, ks in 0..7, jh in 0..1):
// 128 k-rows x 64 j. Direct-from-global MFMA fragments for cw3/cT; q and P^T
// in swizzled LDS. Partials to Tpart/lpart.
// ---------------------------------------------------------------------------
__global__ __launch_bounds__(256) void k1(const float* __restrict__ cw1, const float* __restrict__ qw2,
                                          const int* __restrict__ cmask,
                                          const bf16* __restrict__ cw3, const bf16* __restrict__ cT,
                                          const bf16* __restrict__ qb,
                                          float* __restrict__ Tpart, float* __restrict__ lpart) {
  __shared__ bf16  qs[64 * 128];   // [j][d] swizzled, staged once
  __shared__ bf16  PT[64 * 64];    // [j][k] swizzled handoff
  __shared__ float lred[4][64];
  const int bx = blockIdx.x;
  const int ks = bx >> 1, jh = bx & 1;
  const int b = blockIdx.y;
  const int j0g = jh * 64;
  const int t = threadIdx.x;
  const int wk = t >> 6, lane = t & 63, quad = lane >> 4, l15 = lane & 15;

#pragma unroll
  for (int idx = t; idx < 1024; idx += 256) {
    const int row = idx >> 4, ch = idx & 15;
    *(bf16x8*)&qs[row * 128 + swz(row, ch * 8)] =
        *(const bf16x8*)(qb + ((size_t)(b * LQ_ + j0g + row) * D_ + ch * 8));
  }
  const f32x4 z = {0.f, 0.f, 0.f, 0.f};
  f32x4 Tacc[4][2];
#pragma unroll
  for (int jt = 0; jt < 4; ++jt) { Tacc[jt][0] = z; Tacc[jt][1] = z; }
  float lacc[4] = {0.f, 0.f, 0.f, 0.f};
  float qv[4];
#pragma unroll
  for (int jt = 0; jt < 4; ++jt) qv[jt] = qw2[b * LQ_ + j0g + jt * 16 + l15];
  __syncthreads();

  for (int kt = 0; kt < 2; ++kt) {
    const int k0g = ks * 128 + kt * 64;

    f32x4 S[4] = {z, z, z, z};
#pragma unroll
    for (int kk = 0; kk < 4; ++kk) {
      const bf16x8 a = *(const bf16x8*)(cw3 +
          ((size_t)(b * LC_ + k0g + wk * 16 + l15) * D_ + kk * 32 + quad * 8));
#pragma unroll
      for (int jt = 0; jt < 4; ++jt) {
        const int jr = jt * 16 + l15;
        const bf16x8 bq = *(const bf16x8*)&qs[jr * 128 + swz(jr, kk * 32 + quad * 8)];
        S[jt] = mfma16(a, bq, S[jt]);
      }
    }
    float c1v[4]; int cmv[4];
#pragma unroll
    for (int rr = 0; rr < 4; ++rr) {
      const int krow = k0g + wk * 16 + quad * 4 + rr;
      c1v[rr] = cw1[b * LC_ + krow];
      cmv[rr] = cmask[b * LC_ + krow];
    }
#pragma unroll
    for (int jt = 0; jt < 4; ++jt) {
      bf16x4 pk;
#pragma unroll
      for (int rr = 0; rr < 4; ++rr) {
        const float p = cmv[rr] ? 0.f : __expf(S[jt][rr] + c1v[rr] + qv[jt]);
        lacc[jt] += p;
        pk[rr] = (bf16)p;
      }
      const int jr = jt * 16 + l15;
      *(bf16x4*)&PT[jr * 64 + swz(jr, wk * 16 + quad * 4)] = pk;
    }
    __syncthreads();

#pragma unroll
    for (int kk = 0; kk < 2; ++kk) {
      const bf16x8 bd0 = *(const bf16x8*)(cT +
          ((size_t)(b * D_ + wk * 32 + l15) * LC_ + k0g + kk * 32 + quad * 8));
      const bf16x8 bd1 = *(const bf16x8*)(cT +
          ((size_t)(b * D_ + wk * 32 + 16 + l15) * LC_ + k0g + kk * 32 + quad * 8));
#pragma unroll
      for (int jt = 0; jt < 4; ++jt) {
        const int jr = jt * 16 + l15;
        const bf16x8 aP = *(const bf16x8*)&PT[jr * 64 + swz(jr, kk * 32 + quad * 8)];
        Tacc[jt][0] = mfma16(aP, bd0, Tacc[jt][0]);
        Tacc[jt][1] = mfma16(aP, bd1, Tacc[jt][1]);
      }
    }
    __syncthreads();
  }

#pragma unroll
  for (int jt = 0; jt < 4; ++jt) {
    lacc[jt] += __shfl_xor(lacc[jt], 16);
    lacc[jt] += __shfl_xor(lacc[jt], 32);
  }
  if (lane < 16) {
#pragma unroll
    for (int jt = 0; jt < 4; ++jt) lred[wk][jt * 16 + l15] = lacc[jt];
  }
  __syncthreads();
  if (t < 64)
    lpart[(size_t)(b * 8 + ks) * 128 + j0g + t] =
        lred[0][t] + lred[1][t] + lred[2][t] + lred[3][t];

  float* tp = Tpart + ((size_t)(b * 8 + ks)) * (128 * 128);
#pragma unroll
  for (int jt = 0; jt < 4; ++jt)
#pragma unroll
    for (int dt = 0; dt < 2; ++dt)
#pragma unroll
      for (int rr = 0; rr < 4; ++rr)
        tp[(j0g + jt * 16 + quad * 4 + rr) * 128 + wk * 32 + dt * 16 + l15] =
            Tacc[jt][dt][rr];
}

// ---------------------------------------------------------------------------
// K1r: reduce the eight k-partials, normalize by l_j, emit TT = bf16(T)^T.
// 512 threads (more memory-level parallelism on the partial reads).
// ---------------------------------------------------------------------------
__global__ __launch_bounds__(512) void k1r(const float* __restrict__ Tpart,
                                           const float* __restrict__ lpart,
                                           bf16* __restrict__ TT) {
  __shared__ float Tsum[32 * 132];
  __shared__ float linv[32];
  const int js = blockIdx.x, b = blockIdx.y;
  const int j0 = js * 32;
  const int t = threadIdx.x;
#pragma unroll
  for (int idx = t; idx < 1024; idx += 512) {
    const int row = idx >> 5, seg = idx & 31;
    float4 s = {0.f, 0.f, 0.f, 0.f};
#pragma unroll
    for (int i = 0; i < 8; ++i) {
      const float4 v = ((const float4*)(Tpart + ((size_t)(b * 8 + i)) * (128 * 128)) + j0 * 32)[idx];
      s.x += v.x; s.y += v.y; s.z += v.z; s.w += v.w;
    }
    *(float4*)&Tsum[row * 132 + seg * 4] = s;
  }
  if (t < 32) {
    float l = 0.f;
#pragma unroll
    for (int i = 0; i < 8; ++i) l += lpart[(size_t)(b * 8 + i) * 128 + j0 + t];
    linv[t] = 1.f / l;
  }
  __syncthreads();
  if (t < 256) {
    const int d = t >> 1, jhh = (t & 1) * 16;
    bf16x8 o0, o1;
#pragma unroll
    for (int e = 0; e < 8; ++e) {
      o0[e] = (bf16)(Tsum[(jhh + e) * 132 + d] * linv[jhh + e]);
      o1[e] = (bf16)(Tsum[(jhh + 8 + e) * 132 + d] * linv[jhh + 8 + e]);
    }
    bf16* dst = TT + ((size_t)(b * D_ + d) * LQ_ + j0 + jhh);
    *(bf16x8*)dst = o0;
    *(bf16x8*)(dst + 8) = o1;
  }
}

// ---------------------------------------------------------------------------
// K2 v3 (round-3 verbatim): per (b, 64-row i-tile).
// ---------------------------------------------------------------------------
__global__ __launch_bounds__(256, 4) void k2(const float* __restrict__ c, const float* __restrict__ cw1,
                                             const float* __restrict__ qw2, const int* __restrict__ qmask,
                                             const bf16* __restrict__ cw3, const bf16* __restrict__ qb,
                                             const bf16* __restrict__ qT, const bf16* __restrict__ TT,
                                             float* __restrict__ out) {
  // union LDS: loop phase qTs/TTs/P1 = 37888 B ; epilogue A32/B32 = 33792 B
  __shared__ __align__(16) char smem[37888];
  bf16* qTs = (bf16*)(smem);             // [128][64] swizzled, current j-half
  bf16* TTs = (bf16*)(smem + 16384);     // [128][64] swizzled, current j-half
  bf16* P1  = (bf16*)(smem + 32768);     // [64][40]
  float* A32 = (float*)(smem);           // [32][132] epilogue
  float* B32 = (float*)(smem + 16896);   // [32][132] epilogue
  const int it = blockIdx.x, b = blockIdx.y;
  const int i0 = it * 64;
  const int t = threadIdx.x;
  const int w = t >> 6, lane = t & 63, quad = lane >> 4, l15 = lane & 15;

  bf16x8 aF[4];
#pragma unroll
  for (int kk = 0; kk < 4; ++kk)
    aF[kk] = *(const bf16x8*)(cw3 +
        ((size_t)(b * LC_ + i0 + w * 16 + l15) * D_ + kk * 32 + quad * 8));
  float c1v[4];
#pragma unroll
  for (int rr = 0; rr < 4; ++rr)
    c1v[rr] = cw1[b * LC_ + i0 + w * 16 + quad * 4 + rr];

  const f32x4 z = {0.f, 0.f, 0.f, 0.f};
  f32x4 Aacc[8], Bacc[8];
#pragma unroll
  for (int n = 0; n < 8; ++n) { Aacc[n] = z; Bacc[n] = z; }
  float lacc[4] = {0.f, 0.f, 0.f, 0.f};

#pragma unroll
  for (int jh = 0; jh < 2; ++jh) {
#pragma unroll
    for (int idx = t; idx < 1024; idx += 256) {
      const int row = idx >> 3, ch = idx & 7;
      const int sc = (ch * 8) ^ ((row & 7) << 3);
      *(bf16x8*)&qTs[row * 64 + sc] =
          *(const bf16x8*)(qT + ((size_t)(b * D_ + row) * LQ_ + jh * 64 + ch * 8));
      *(bf16x8*)&TTs[row * 64 + sc] =
          *(const bf16x8*)(TT + ((size_t)(b * D_ + row) * LQ_ + jh * 64 + ch * 8));
    }
    __syncthreads();

#pragma unroll
    for (int jtl = 0; jtl < 2; ++jtl) {
      const int j0 = jh * 64 + jtl * 32;
      const float qv0 = qw2[b * LQ_ + j0 + l15];
      const float qv1 = qw2[b * LQ_ + j0 + 16 + l15];
      const int   qm0 = qmask[b * LQ_ + j0 + l15];
      const int   qm1 = qmask[b * LQ_ + j0 + 16 + l15];

      f32x4 S0 = z, S1 = z;
#pragma unroll
      for (int kk = 0; kk < 4; ++kk) {
        const bf16x8 b0 = *(const bf16x8*)(qb +
            ((size_t)(b * LQ_ + j0 + l15) * D_ + kk * 32 + quad * 8));
        const bf16x8 b1 = *(const bf16x8*)(qb +
            ((size_t)(b * LQ_ + j0 + 16 + l15) * D_ + kk * 32 + quad * 8));
        S0 = mfma16(aF[kk], b0, S0);
        S1 = mfma16(aF[kk], b1, S1);
      }
#pragma unroll
      for (int rr = 0; rr < 4; ++rr) {
        const float p0 = qm0 ? 0.f : __expf(S0[rr] + c1v[rr] + qv0);
        const float p1 = qm1 ? 0.f : __expf(S1[rr] + c1v[rr] + qv1);
        lacc[rr] += p0 + p1;
        P1[(w * 16 + quad * 4 + rr) * 40 + l15] = (bf16)p0;
        P1[(w * 16 + quad * 4 + rr) * 40 + 16 + l15] = (bf16)p1;
      }
      __syncthreads();

      const bf16x8 aP = *(bf16x8*)&P1[(w * 16 + l15) * 40 + quad * 8];
      const int cbase = jtl * 32 + quad * 8;
#pragma unroll
      for (int nt = 0; nt < 8; ++nt) {
        const int row = nt * 16 + l15;
        const int sc = cbase ^ ((row & 7) << 3);
        const bf16x8 bq = *(bf16x8*)&qTs[row * 64 + sc];
        const bf16x8 bt = *(bf16x8*)&TTs[row * 64 + sc];
        Aacc[nt] = mfma16(aP, bq, Aacc[nt]);
        Bacc[nt] = mfma16(aP, bt, Bacc[nt]);
      }
      __syncthreads();
    }
  }

#pragma unroll
  for (int rr = 0; rr < 4; ++rr) {
    float v = lacc[rr];
    v += __shfl_xor(v, 1); v += __shfl_xor(v, 2);
    v += __shfl_xor(v, 4); v += __shfl_xor(v, 8);
    lacc[rr] = 1.f / v;
  }

#pragma unroll
  for (int h = 0; h < 2; ++h) {
    if ((w >> 1) == h) {
      const int lrow0 = (w & 1) * 16 + quad * 4;
#pragma unroll
      for (int nt = 0; nt < 8; ++nt)
#pragma unroll
        for (int rr = 0; rr < 4; ++rr) {
          A32[(lrow0 + rr) * 132 + nt * 16 + l15] = Aacc[nt][rr] * lacc[rr];
          B32[(lrow0 + rr) * 132 + nt * 16 + l15] = Bacc[nt][rr] * lacc[rr];
        }
    }
    __syncthreads();
#pragma unroll
    for (int idx = t; idx < 1024; idx += 256) {
      const int lrow = idx >> 5, seg = idx & 31;
      const size_t grow = (size_t)(b * LC_ + i0 + h * 32 + lrow);
      const float4 c4 = ((const float4*)(c + grow * D_))[seg];
      const float4 a4 = *(float4*)&A32[lrow * 132 + seg * 4];
      const float4 b4 = *(float4*)&B32[lrow * 132 + seg * 4];
      float4* ob = (float4*)(out + grow * 512);
      ob[seg] = c4;
      ob[32 + seg] = a4;
      float4 ca; ca.x = c4.x * a4.x; ca.y = c4.y * a4.y; ca.z = c4.z * a4.z; ca.w = c4.w * a4.w;
      ob[64 + seg] = ca;
      float4 cb; cb.x = c4.x * b4.x; cb.y = c4.y * b4.y; cb.z = c4.z * b4.z; cb.w = c4.w * b4.w;
      ob[96 + seg] = cb;
    }
    __syncthreads();
  }
}

// ---------------------------------------------------------------------------
extern "C" void kernel_launch(void* const* d_in, const int* in_sizes, int n_in,
                              void* d_out, int out_size, void* d_ws, size_t ws_size,
                              hipStream_t stream) {
  (void)in_sizes; (void)n_in; (void)out_size; (void)ws_size;
  const float* c     = (const float*)d_in[0];
  const float* q     = (const float*)d_in[1];
  const int*   cmask = (const int*)d_in[2];
  const int*   qmask = (const int*)d_in[3];
  const float* w     = (const float*)d_in[4];
  float* out = (float*)d_out;

  // workspace layout (40.1 MB)
  char* ws = (char*)d_ws;
  float* cw1 = (float*)(ws + 0);          //  64*1024 f32
  float* qw2 = (float*)(ws + 262144);     //  64*128  f32
  bf16*  cw3 = (bf16*)(ws + 294912);      //  64*1024*128 bf16  (c*w3)
  bf16*  cT  = (bf16*)(ws + 17072128);    //  64*128*1024 bf16  (c transposed)
  bf16*  qb  = (bf16*)(ws + 33849344);    //  64*128*128 bf16
  bf16*  qT  = (bf16*)(ws + 35946496);    //  64*128*128 bf16  (q transposed)
  bf16*  TT  = (bf16*)(ws + 38043648);    //  64*128*128 bf16  (T transposed)

  // k-split partials live in d_out scratch (fully overwritten by k2 afterwards)
  float* Tpart = out;                     //  64*8*128*128 f32 = 33.6 MB
  float* lpart = out + 8388608;           //  64*8*128 f32

  kpre<<<dim3(9, 64), 256, 0, stream>>>(c, q, w, cw1, cw3, cT, qw2, qb, qT);
  k1  <<<dim3(16, 64), 256, 0, stream>>>(cw1, qw2, cmask, cw3, cT, qb, Tpart, lpart);
  k1r <<<dim3(4, 64), 512, 0, stream>>>(Tpart, lpart, TT);
  k2  <<<dim3(16, 64), 256, 0, stream>>>(c, cw1, qw2, qmask, cw3, qb, qT, TT, out);
}